// Round 10
// baseline (211.122 us; speedup 1.0000x reference)
//
#include <hip/hip_runtime.h>
#include <math.h>

// ---------------------------------------------------------------------------
#define B_ROWS   8192
#define NZ       100
#define NC       2
#define H1       256
#define H2       64
#define FEATN    8192
#define FDIM     1024
#define RROWS    16            // rows per k_main block = MFMA M
#define NTILE    (FEATN / 16)  // 512 16-col MFMA tiles
#define A1ROWS   16
#define A1BLKS   (B_ROWS / A1ROWS)   // 512
#define CONVBLKS 128                 // w3 conversion blocks fused into k_a1 (512 thr)
#define A2ROWS   16
#define A2BLKS   (B_ROWS / A2ROWS)   // 512

typedef __attribute__((ext_vector_type(8))) short short8;
typedef __attribute__((ext_vector_type(4))) float f32x4;

// ---------------------------------------------------------------------------
// JAX threefry2x32, partitionable, key=(0,42), counter=(0, flat)
__device__ __forceinline__ unsigned rotl32(unsigned v, int r) {
    return (v << r) | (v >> (32 - r));
}
__device__ __forceinline__ unsigned threefry_bits(unsigned lo) {
    const unsigned ks0 = 0u, ks1 = 42u, ks2 = 0x1BD11BDAu ^ 42u;
    unsigned x0 = 0u + ks0;
    unsigned x1 = lo + ks1;
#define TF_R4(a,b,c,d) \
    x0 += x1; x1 = rotl32(x1,a); x1 ^= x0; \
    x0 += x1; x1 = rotl32(x1,b); x1 ^= x0; \
    x0 += x1; x1 = rotl32(x1,c); x1 ^= x0; \
    x0 += x1; x1 = rotl32(x1,d); x1 ^= x0;
    TF_R4(13,15,26,6);  x0 += ks1; x1 += ks2 + 1u;
    TF_R4(17,29,16,24); x0 += ks2; x1 += ks0 + 2u;
    TF_R4(13,15,26,6);  x0 += ks0; x1 += ks1 + 3u;
    TF_R4(17,29,16,24); x0 += ks1; x1 += ks2 + 4u;
    TF_R4(13,15,26,6);  x0 += ks2; x1 += ks0 + 5u;
#undef TF_R4
    return x0 ^ x1;
}
__device__ __forceinline__ float gumbel_g(unsigned flat) {
    unsigned bits = threefry_bits(flat);
    float u  = __uint_as_float((bits >> 9) | 0x3f800000u) - 1.0f;
    float U  = 0.001f * u;
    float t1 = U + 0.001f;
    float L1 = (float)log((double)t1);
    float A  = 0.001f - L1;
    float L2 = (float)log((double)A);
    return -L2;
}

// float -> bf16 RNE
__device__ __forceinline__ unsigned short f2bf(float x) {
    unsigned u = __float_as_uint(x);
    u += 0x7fffu + ((u >> 16) & 1u);
    return (unsigned short)(u >> 16);
}
// order-preserving float -> u32
__device__ __forceinline__ unsigned fmono(float x) {
    unsigned b = __float_as_uint(x);
    return (b & 0x80000000u) ? ~b : (b | 0x80000000u);
}

// ---------------------------------------------------------------------------
// K1 (512 thr): blocks [0,A1BLKS): a1 = concat(x,y)@W1 + b1 (fp32 FMA) + BN
//   partials (fp64, original row order).  NO cross-block fences (R8 lesson).
//     blocks [A1BLKS,..): convert W3 -> bf16 MFMA-B-fragment layout; per-block
//   max|W3| written to wmax[block] (all 128 slots written every run -> no
//   memset, no global atomic).
__global__ __launch_bounds__(512) void k_a1(
    const float* __restrict__ x, const float* __restrict__ y,
    const float* __restrict__ W1, const float* __restrict__ b1,
    const float* __restrict__ W3,
    float* __restrict__ a1, double* __restrict__ p1, double* __restrict__ p2,
    unsigned short* __restrict__ w3s, float* __restrict__ wmax)
{
    const int t = threadIdx.x;

    if (blockIdx.x >= A1BLKS) {
        const int job  = (blockIdx.x - A1BLKS) * 512 + t;   // 0..65535
        const int T    = job >> 7;
        const int rem  = job & 127;
        const int kh   = rem >> 6;
        const int l    = rem & 63;
        const int quad = l >> 4, col = l & 15;
        const float* src = W3 + (size_t)(kh * 32 + quad * 8) * FEATN + T * 16 + col;
        unsigned short v[8];
        float mx = 0.0f;
#pragma unroll
        for (int jj = 0; jj < 8; ++jj) {
            float xv = src[(size_t)jj * FEATN];
            mx = fmaxf(mx, fabsf(xv));
            v[jj] = f2bf(xv);
        }
        uint4 o;
        o.x = (unsigned)v[0] | ((unsigned)v[1] << 16);
        o.y = (unsigned)v[2] | ((unsigned)v[3] << 16);
        o.z = (unsigned)v[4] | ((unsigned)v[5] << 16);
        o.w = (unsigned)v[6] | ((unsigned)v[7] << 16);
        ((uint4*)w3s)[job] = o;
#pragma unroll
        for (int off = 32; off; off >>= 1) mx = fmaxf(mx, __shfl_xor(mx, off));
        __shared__ float wred[8];
        if ((t & 63) == 0) wred[t >> 6] = mx;
        __syncthreads();
        if (t == 0) {
            float m = wred[0];
#pragma unroll
            for (int wq = 1; wq < 8; ++wq) m = fmaxf(m, wred[wq]);
            wmax[blockIdx.x - A1BLKS] = m;
        }
        return;
    }

    const int j    = t & 255;
    const int half = t >> 8;            // 0: rows 0-7, 1: rows 8-15
    const int b0   = blockIdx.x * A1ROWS;
    const int r0   = half * 8;

    // Transposed LDS x-tile: xs[i][r] -> broadcast ds_read_b128 in the loop.
    __shared__ __align__(16) float xs[NZ][16];
    __shared__ __align__(16) float ys[NC][16];
    __shared__ float vsh[256][8];       // half1's v values, for exact-order sums
    for (int q = t; q < A1ROWS * NZ; q += 512) {
        int r = q / NZ, i = q - r * NZ;
        xs[i][r] = x[(size_t)b0 * NZ + q];
    }
    if (t < A1ROWS * NC) {
        int r = t >> 1, i = t & 1;
        ys[i][r] = y[b0 * NC + t];
    }
    __syncthreads();

    float acc[8];
#pragma unroll
    for (int r = 0; r < 8; ++r) acc[r] = 0.0f;
    for (int i = 0; i < NZ; ++i) {
        float wd = W1[i * H1 + j];
        const float4 x0 = *(const float4*)&xs[i][r0];
        const float4 x1 = *(const float4*)&xs[i][r0 + 4];
        acc[0] = fmaf(x0.x, wd, acc[0]); acc[1] = fmaf(x0.y, wd, acc[1]);
        acc[2] = fmaf(x0.z, wd, acc[2]); acc[3] = fmaf(x0.w, wd, acc[3]);
        acc[4] = fmaf(x1.x, wd, acc[4]); acc[5] = fmaf(x1.y, wd, acc[5]);
        acc[6] = fmaf(x1.z, wd, acc[6]); acc[7] = fmaf(x1.w, wd, acc[7]);
    }
#pragma unroll
    for (int i = 0; i < NC; ++i) {
        float wd = W1[(NZ + i) * H1 + j];
        const float4 y0 = *(const float4*)&ys[i][r0];
        const float4 y1 = *(const float4*)&ys[i][r0 + 4];
        acc[0] = fmaf(y0.x, wd, acc[0]); acc[1] = fmaf(y0.y, wd, acc[1]);
        acc[2] = fmaf(y0.z, wd, acc[2]); acc[3] = fmaf(y0.w, wd, acc[3]);
        acc[4] = fmaf(y1.x, wd, acc[4]); acc[5] = fmaf(y1.y, wd, acc[5]);
        acc[6] = fmaf(y1.z, wd, acc[6]); acc[7] = fmaf(y1.w, wd, acc[7]);
    }
    const float bb = b1[j];
    float v[8];
#pragma unroll
    for (int r = 0; r < 8; ++r) {
        v[r] = acc[r] + bb;
        a1[(b0 + r0 + r) * H1 + j] = v[r];
    }
    if (half) {
#pragma unroll
        for (int r = 0; r < 8; ++r) vsh[j][r] = v[r];
    }
    __syncthreads();
    if (!half) {
        double s = 0.0, s2 = 0.0;
#pragma unroll
        for (int r = 0; r < 8; ++r) {           // rows 0..7 in original order
            double dv = (double)v[r];
            s += dv; s2 += dv * dv;
        }
#pragma unroll
        for (int r = 0; r < 8; ++r) {           // rows 8..15 in original order
            double dv = (double)vsh[j][r];
            s += dv; s2 += dv * dv;
        }
        p1[blockIdx.x * H1 + j] = s;
        p2[blockIdx.x * H1 + j] = s2;
    }
}

// ---------------------------------------------------------------------------
__global__ __launch_bounds__(256) void k_stats2(
    const double* __restrict__ p1, const double* __restrict__ p2,
    int nprt, int ncol,
    const float* __restrict__ gamma, const float* __restrict__ beta,
    float* __restrict__ scale, float* __restrict__ shift)
{
    const int j = blockIdx.x, t = threadIdx.x;
    double s = 0.0, s2 = 0.0;
    for (int g = t; g < nprt; g += 256) {
        s  += p1[(size_t)g * ncol + j];
        s2 += p2[(size_t)g * ncol + j];
    }
#pragma unroll
    for (int off = 32; off; off >>= 1) {
        s  += __shfl_xor(s, off);
        s2 += __shfl_xor(s2, off);
    }
    __shared__ double ws1[4], ws2[4];
    if ((t & 63) == 0) { ws1[t >> 6] = s; ws2[t >> 6] = s2; }
    __syncthreads();
    if (t == 0) {
        s  = (ws1[0] + ws1[1]) + (ws1[2] + ws1[3]);
        s2 = (ws2[0] + ws2[1]) + (ws2[2] + ws2[3]);
        double mean = s * (1.0 / B_ROWS);
        double var  = s2 * (1.0 / B_ROWS) - mean * mean;
        double rstd = 1.0 / sqrt(var + 1e-5);
        double sc   = (double)gamma[j] * rstd;
        scale[j] = (float)sc;
        shift[j] = (float)((double)beta[j] - mean * sc);
    }
}

// ---------------------------------------------------------------------------
// K3 (512 thr): 16 rows/block; thread = 1 col x 2 rows. fp32 FMA accumulate;
// BN partial sums reassembled in fp64, original row order, via LDS.
__global__ __launch_bounds__(512) void k_a2(
    const float* __restrict__ a1,
    const float* __restrict__ sc1, const float* __restrict__ sh1,
    const float* __restrict__ W2, const float* __restrict__ b2,
    float* __restrict__ a2, double* __restrict__ p1, double* __restrict__ p2)
{
    const int t  = threadIdx.x;
    const int k  = t & 63;       // output col
    const int rg = t >> 6;       // row-group (== wave), rows rg*2, rg*2+1
    const int b0 = blockIdx.x * A2ROWS;
    const int r0 = rg * 2;

    __shared__ __align__(8) float hs[H1][18];   // stride 72B: 2-way banks max
    __shared__ float vsh[64][17];

    {
        const int jc = t & 255, rq = t >> 8;
        const float sct = sc1[jc], sht = sh1[jc];
#pragma unroll
        for (int rr = rq * 8; rr < rq * 8 + 8; ++rr) {
            float vv = a1[(size_t)(b0 + rr) * H1 + jc];
            hs[jc][rr] = fmaxf(fmaf(vv, sct, sht), 0.0f);
        }
    }
    __syncthreads();

    float acc0 = 0.0f, acc1 = 0.0f;
#pragma unroll 4
    for (int j = 0; j < H1; ++j) {
        float wd = W2[j * H2 + k];
        const float2 h2 = *(const float2*)&hs[j][r0];
        acc0 = fmaf(h2.x, wd, acc0);
        acc1 = fmaf(h2.y, wd, acc1);
    }
    const float bb = b2[k];
    float v0 = acc0 + bb;
    float v1 = acc1 + bb;
    a2[(b0 + r0 + 0) * H2 + k] = v0;
    a2[(b0 + r0 + 1) * H2 + k] = v1;
    vsh[k][r0]     = v0;
    vsh[k][r0 + 1] = v1;
    __syncthreads();
    if (t < 64) {
        double s = 0.0, s2 = 0.0;
#pragma unroll
        for (int r = 0; r < A2ROWS; ++r) {      // original order r = 0..15
            double dv = (double)vsh[t][r];
            s += dv; s2 += dv * dv;
        }
        p1[blockIdx.x * H2 + t] = s;
        p2[blockIdx.x * H2 + t] = s2;
    }
}

// ---------------------------------------------------------------------------
// K5: R9 batch-4 compute core, with FUSED prologue replacing two graph nodes:
//   (a) BN2 stats: each block redundantly reduces the 512x64 fp64 partials
//       (coalesced, deterministic fixed-order tree; ~0.3 us) -> sc2S/sh2S LDS.
//   (b) max|W3|: reduce wmax[128] via LDS (replaces memset + atomicMax).
// Graph shrinks 6 -> 4 nodes. Compute core (pass A/B, margins) UNCHANGED.
__global__ __launch_bounds__(512)
__attribute__((amdgpu_waves_per_eu(4, 4)))
void k_main(
    const float* __restrict__ a2,
    const float* __restrict__ W3, const float* __restrict__ b3,
    const unsigned short* __restrict__ w3s, const float* __restrict__ wmax,
    const double* __restrict__ p1, const double* __restrict__ p2,
    const float* __restrict__ g2, const float* __restrict__ be2,
    const float* __restrict__ codebook, float* __restrict__ out)
{
    const int t    = threadIdx.x;
    const int wv   = t >> 6;           // wave 0..7
    const int lane = t & 63;
    const int quad = lane >> 4, col = lane & 15;
    const int b0   = blockIdx.x * RROWS;

    __shared__ __align__(16) float h2T[64][17];     // [j][r], padded
    __shared__ __align__(16) float fineT[NTILE][17];// per-(tile16, row) bf16 max
    __shared__ float thrS[RROWS];
    __shared__ unsigned long long best[RROWS];
    __shared__ __align__(16) unsigned short wl[RROWS * NTILE]; // true max: no overflow
    __shared__ int wlN;
    __shared__ int rowInd[RROWS];
    __shared__ float maxwS;
    __shared__ float sc2S[H2], sh2S[H2];

    if (t == 0) wlN = 0;

    // ---- fused BN2 stats + maxw prologue (scratch: wl as fp64, fineT) ----
    {
        const int j = t & 63, part = t >> 6;        // t == part*64 + j
        double s = 0.0, s2 = 0.0;
        const double* q1 = p1 + (size_t)part * 64 * H2 + j;
        const double* q2 = p2 + (size_t)part * 64 * H2 + j;
#pragma unroll 8
        for (int g = 0; g < 64; ++g) {
            s  += q1[(size_t)g * H2];
            s2 += q2[(size_t)g * H2];
        }
        double* ps1 = (double*)wl;                  // 8 KB scratch in wl
        double* ps2 = ps1 + 512;
        ps1[t] = s;
        ps2[t] = s2;
        float* mr = (float*)fineT;                  // scratch before pass A
        if (t < 128) mr[t] = wmax[t];
    }
    __syncthreads();
    if (t < 64) {
        const double* ps1 = (const double*)wl;
        const double* ps2 = ps1 + 512;
        double s = 0.0, s2 = 0.0;
#pragma unroll
        for (int p = 0; p < 8; ++p) { s += ps1[p * 64 + t]; s2 += ps2[p * 64 + t]; }
        double mean = s * (1.0 / B_ROWS);
        double var  = s2 * (1.0 / B_ROWS) - mean * mean;
        double rstd = 1.0 / sqrt(var + 1e-5);
        double sc   = (double)g2[t] * rstd;
        sc2S[t] = (float)sc;
        sh2S[t] = (float)((double)be2[t] - mean * sc);
    }
    if (t == 256) {                                 // separate wave
        const float* mr = (const float*)fineT;
        float m = mr[0];
        for (int i = 1; i < 128; ++i) m = fmaxf(m, mr[i]);
        maxwS = m;
    }
    __syncthreads();

    for (int q = t; q < RROWS * 64; q += 512) {
        int j = q >> 4, r = q & 15;
        float v = a2[(b0 + r) * H2 + j];
        h2T[j][r] = fmaxf(fmaf(v, sc2S[j], sh2S[j]), 0.0f);
    }
    __syncthreads();

    // h fragments (bf16): lane holds h[r=col][k=quad*8+jj], k-halves 0/1
    short8 aF0, aF1;
#pragma unroll
    for (int jj = 0; jj < 8; ++jj) {
        aF0[jj] = (short)f2bf(h2T[quad * 8 + jj][col]);
        aF1[jj] = (short)f2bf(h2T[32 + quad * 8 + jj][col]);
    }

    // ---- Pass A: 8 segments x (2 half-batches x 4 tiles); swapped-operand
    //      MFMA -> lane holds logit[r=lane&15][c=T*16+quad*4+q] in acc[q] ----
    {
        const uint4*  wp = (const uint4*)w3s + (size_t)wv * 8192 + lane;
        const float4* bq = (const float4*)b3 + wv * 256 + quad;
        for (int s = 0; s < 8; ++s) {
#pragma unroll
            for (int hu = 0; hu < 2; ++hu) {
                uint4 c[4], d[4];
                float4 bb[4];
#pragma unroll
                for (int u = 0; u < 4; ++u) {
                    const int uu = hu * 4 + u;
                    c[u]  = wp[uu * 128];
                    d[u]  = wp[uu * 128 + 64];
                    bb[u] = bq[uu * 4];
                }
#pragma unroll
                for (int u = 0; u < 4; ++u) {
                    f32x4 acc = {bb[u].x, bb[u].y, bb[u].z, bb[u].w};
                    acc = __builtin_amdgcn_mfma_f32_16x16x32_bf16(
                              *(const short8*)&c[u], aF0, acc, 0, 0, 0);
                    acc = __builtin_amdgcn_mfma_f32_16x16x32_bf16(
                              *(const short8*)&d[u], aF1, acc, 0, 0, 0);
                    float m = fmaxf(fmaxf(acc[0], acc[1]), fmaxf(acc[2], acc[3]));
                    m = fmaxf(m, __shfl_xor(m, 16));
                    m = fmaxf(m, __shfl_xor(m, 32));
                    if (lane < 16)
                        fineT[(wv * 8 + s) * 8 + hu * 4 + u][lane] = m;
                }
            }
            wp += 1024; bq += 32;
        }
    }
    __syncthreads();

    // ---- Thresholds: all 512 threads; row = t>>5, 32 lanes per row ----
    {
        const int r = t >> 5, cc = t & 31;
        float s = fabsf(h2T[2 * cc][r]) + fabsf(h2T[2 * cc + 1][r]);
        float gmv = -1e30f;
#pragma unroll
        for (int k = 0; k < 16; ++k) gmv = fmaxf(gmv, fineT[cc + 32 * k][r]);
#pragma unroll
        for (int off = 1; off < 32; off <<= 1) {
            s   += __shfl_xor(s, off);
            gmv  = fmaxf(gmv, __shfl_xor(gmv, off));
        }
        if (cc == 0) {
            float e = s * maxwS * (1.0f / 256.0f);   // |dlogit| <= S*maxW*2^-8
            thrS[r] = gmv - (0.1068f + e + 1e-3f);
            best[r] = 0ull;
        }
    }
    __syncthreads();

    // ---- Worklist of qualifying (row, tile16) cells ----
    {
        const int r = t >> 5, cc = t & 31;
        const float th = thrS[r];
#pragma unroll
        for (int k = 0; k < 16; ++k) {
            const int T = cc + 32 * k;
            if (fineT[T][r] >= th) {
                int idx = atomicAdd(&wlN, 1);
                wl[idx] = (unsigned short)((r << 9) | T);
            }
        }
    }
    __syncthreads();

    // ---- Pass B: wave handles 4 cells (16 lanes each); exact fp32 ----
    {
        const int n = wlN;
        const int g = lane >> 4;       // cell slot within wave
        for (int i = wv * 4; i < n; i += 32) {
            const int  ci  = i + g;
            const bool act = (ci < n);
            const int  e   = act ? wl[ci] : 0;
            const int  r   = e >> 9;
            const int  T   = e & 511;
            const int  f   = T * 16 + col;
            float acc = b3[f];
            const float* wcol = W3 + f;
#pragma unroll 8
            for (int j = 0; j < 64; ++j) {
                acc = fmaf(h2T[j][r], *wcol, acc);
                wcol += FEATN;
            }
            if (act && acc >= thrS[r]) {
                float sc = acc + gumbel_g((unsigned)(b0 + r) * (unsigned)FEATN + (unsigned)f);
                unsigned long long pk = ((unsigned long long)fmono(sc) << 32)
                                      | (unsigned)(FEATN - 1 - f);
                atomicMax(&best[r], pk);
            }
        }
    }
    __syncthreads();
    if (t < RROWS) {
        rowInd[t] = (FEATN - 1 - (int)(best[t] & 0xFFFFFFFFull)) & (FEATN - 1);
    }
    __syncthreads();

    // ---- out[b,:] = codebook[ind,:] ----
    {
        const int rr = t >> 8, tt = t & 255;
        for (int rp = 0; rp < RROWS / 2; ++rp) {
            const int r = rp * 2 + rr;
            const int ind = rowInd[r];
            const float4* src = (const float4*)(codebook + (size_t)ind * FDIM);
            float4*       dst = (float4*)(out + (size_t)(b0 + r) * FDIM);
            dst[tt] = src[tt];
        }
    }
}

// ---------------------------------------------------------------------------
extern "C" void kernel_launch(void* const* d_in, const int* in_sizes, int n_in,
                              void* d_out, int out_size, void* d_ws, size_t ws_size,
                              hipStream_t stream)
{
    const float* x   = (const float*)d_in[0];
    const float* y   = (const float*)d_in[1];
    const float* W1  = (const float*)d_in[2];
    const float* b1  = (const float*)d_in[3];
    const float* g1  = (const float*)d_in[4];
    const float* be1 = (const float*)d_in[5];
    const float* W2  = (const float*)d_in[6];
    const float* b2  = (const float*)d_in[7];
    const float* g2  = (const float*)d_in[8];
    const float* be2 = (const float*)d_in[9];
    const float* W3  = (const float*)d_in[10];
    const float* b3  = (const float*)d_in[11];
    const float* cb  = (const float*)d_in[12];
    float* out = (float*)d_out;

    float* ws  = (float*)d_ws;
    float* a1  = ws;                          // 8 MB
    float* a2  = a1 + B_ROWS * H1;            // 2 MB
    float* sc1 = a2 + B_ROWS * H2;
    float* sh1 = sc1 + H1;
    double* p1 = (double*)(sh1 + H1);         // 1 MB
    double* p2 = p1 + A1BLKS * H1;            // 1 MB
    unsigned short* w3s = (unsigned short*)(p2 + A1BLKS * H1);  // 1 MB bf16
    float* wmax = (float*)(w3s + NTILE * 2 * 64 * 8);           // 128 f32

    // 4-node graph: no memset (wmax fully rewritten each run), no stats2 node
    // (fused into k_main prologue), no global atomics.
    k_a1    <<<A1BLKS + CONVBLKS, 512, 0, stream>>>(x, y, W1, b1, W3,
                                                    a1, p1, p2, w3s, wmax);
    k_stats2<<<H1, 256, 0, stream>>>(p1, p2, A1BLKS, H1, g1, be1, sc1, sh1);
    k_a2    <<<A2BLKS, 512, 0, stream>>>(a1, sc1, sh1, W2, b2, a2, p1, p2);
    k_main  <<<B_ROWS / RROWS, 512, 0, stream>>>(a2, W3, b3, w3s, wmax,
                                                 p1, p2, g2, be2, cb, out);
}

// Round 11
// 207.498 us; speedup vs baseline: 1.0175x; 1.0175x over previous
//
#include <hip/hip_runtime.h>
#include <math.h>

// ---------------------------------------------------------------------------
#define B_ROWS   8192
#define NZ       100
#define NC       2
#define H1       256
#define H2       64
#define FEATN    8192
#define FDIM     1024
#define RROWS    16            // rows per k_main block = MFMA M
#define NTILE    (FEATN / 16)  // 512 16-col MFMA tiles
#define A1ROWS   16
#define A1BLKS   (B_ROWS / A1ROWS)   // 512
#define CONVBLKS 128                 // w3 conversion blocks fused into k_a1 (512 thr)
#define A2ROWS   16
#define A2BLKS   (B_ROWS / A2ROWS)   // 512

typedef __attribute__((ext_vector_type(8))) short short8;
typedef __attribute__((ext_vector_type(4))) float f32x4;

// ---------------------------------------------------------------------------
// JAX threefry2x32, partitionable, key=(0,42), counter=(0, flat)
__device__ __forceinline__ unsigned rotl32(unsigned v, int r) {
    return (v << r) | (v >> (32 - r));
}
__device__ __forceinline__ unsigned threefry_bits(unsigned lo) {
    const unsigned ks0 = 0u, ks1 = 42u, ks2 = 0x1BD11BDAu ^ 42u;
    unsigned x0 = 0u + ks0;
    unsigned x1 = lo + ks1;
#define TF_R4(a,b,c,d) \
    x0 += x1; x1 = rotl32(x1,a); x1 ^= x0; \
    x0 += x1; x1 = rotl32(x1,b); x1 ^= x0; \
    x0 += x1; x1 = rotl32(x1,c); x1 ^= x0; \
    x0 += x1; x1 = rotl32(x1,d); x1 ^= x0;
    TF_R4(13,15,26,6);  x0 += ks1; x1 += ks2 + 1u;
    TF_R4(17,29,16,24); x0 += ks2; x1 += ks0 + 2u;
    TF_R4(13,15,26,6);  x0 += ks0; x1 += ks1 + 3u;
    TF_R4(17,29,16,24); x0 += ks1; x1 += ks2 + 4u;
    TF_R4(13,15,26,6);  x0 += ks2; x1 += ks0 + 5u;
#undef TF_R4
    return x0 ^ x1;
}
__device__ __forceinline__ float gumbel_g(unsigned flat) {
    unsigned bits = threefry_bits(flat);
    float u  = __uint_as_float((bits >> 9) | 0x3f800000u) - 1.0f;
    float U  = 0.001f * u;
    float t1 = U + 0.001f;
    float L1 = (float)log((double)t1);
    float A  = 0.001f - L1;
    float L2 = (float)log((double)A);
    return -L2;
}

// float -> bf16 RNE
__device__ __forceinline__ unsigned short f2bf(float x) {
    unsigned u = __float_as_uint(x);
    u += 0x7fffu + ((u >> 16) & 1u);
    return (unsigned short)(u >> 16);
}
// order-preserving float -> u32
__device__ __forceinline__ unsigned fmono(float x) {
    unsigned b = __float_as_uint(x);
    return (b & 0x80000000u) ? ~b : (b | 0x80000000u);
}

// ---------------------------------------------------------------------------
// K1 (512 thr): blocks [0,A1BLKS): a1 = concat(x,y)@W1 + b1 (fp32 FMA) + BN
//   partials (fp64, original row order).  NO cross-block fences (R8 lesson).
//     blocks [A1BLKS,..): convert W3 -> bf16 MFMA-B-fragment layout; per-block
//   max|W3| -> wmax[block] (all 128 slots written every run: no memset node,
//   no global atomic).
__global__ __launch_bounds__(512) void k_a1(
    const float* __restrict__ x, const float* __restrict__ y,
    const float* __restrict__ W1, const float* __restrict__ b1,
    const float* __restrict__ W3,
    float* __restrict__ a1, double* __restrict__ p1, double* __restrict__ p2,
    unsigned short* __restrict__ w3s, float* __restrict__ wmax)
{
    const int t = threadIdx.x;

    if (blockIdx.x >= A1BLKS) {
        const int job  = (blockIdx.x - A1BLKS) * 512 + t;   // 0..65535
        const int T    = job >> 7;
        const int rem  = job & 127;
        const int kh   = rem >> 6;
        const int l    = rem & 63;
        const int quad = l >> 4, col = l & 15;
        const float* src = W3 + (size_t)(kh * 32 + quad * 8) * FEATN + T * 16 + col;
        unsigned short v[8];
        float mx = 0.0f;
#pragma unroll
        for (int jj = 0; jj < 8; ++jj) {
            float xv = src[(size_t)jj * FEATN];
            mx = fmaxf(mx, fabsf(xv));
            v[jj] = f2bf(xv);
        }
        uint4 o;
        o.x = (unsigned)v[0] | ((unsigned)v[1] << 16);
        o.y = (unsigned)v[2] | ((unsigned)v[3] << 16);
        o.z = (unsigned)v[4] | ((unsigned)v[5] << 16);
        o.w = (unsigned)v[6] | ((unsigned)v[7] << 16);
        ((uint4*)w3s)[job] = o;
#pragma unroll
        for (int off = 32; off; off >>= 1) mx = fmaxf(mx, __shfl_xor(mx, off));
        __shared__ float wred[8];
        if ((t & 63) == 0) wred[t >> 6] = mx;
        __syncthreads();
        if (t == 0) {
            float m = wred[0];
#pragma unroll
            for (int wq = 1; wq < 8; ++wq) m = fmaxf(m, wred[wq]);
            wmax[blockIdx.x - A1BLKS] = m;
        }
        return;
    }

    const int j    = t & 255;
    const int half = t >> 8;            // 0: rows 0-7, 1: rows 8-15
    const int b0   = blockIdx.x * A1ROWS;
    const int r0   = half * 8;

    // Transposed LDS x-tile: xs[i][r] -> broadcast ds_read_b128 in the loop.
    __shared__ __align__(16) float xs[NZ][16];
    __shared__ __align__(16) float ys[NC][16];
    __shared__ float vsh[256][8];       // half1's v values, for exact-order sums
    for (int q = t; q < A1ROWS * NZ; q += 512) {
        int r = q / NZ, i = q - r * NZ;
        xs[i][r] = x[(size_t)b0 * NZ + q];
    }
    if (t < A1ROWS * NC) {
        int r = t >> 1, i = t & 1;
        ys[i][r] = y[b0 * NC + t];
    }
    __syncthreads();

    float acc[8];
#pragma unroll
    for (int r = 0; r < 8; ++r) acc[r] = 0.0f;
    for (int i = 0; i < NZ; ++i) {
        float wd = W1[i * H1 + j];
        const float4 x0 = *(const float4*)&xs[i][r0];
        const float4 x1 = *(const float4*)&xs[i][r0 + 4];
        acc[0] = fmaf(x0.x, wd, acc[0]); acc[1] = fmaf(x0.y, wd, acc[1]);
        acc[2] = fmaf(x0.z, wd, acc[2]); acc[3] = fmaf(x0.w, wd, acc[3]);
        acc[4] = fmaf(x1.x, wd, acc[4]); acc[5] = fmaf(x1.y, wd, acc[5]);
        acc[6] = fmaf(x1.z, wd, acc[6]); acc[7] = fmaf(x1.w, wd, acc[7]);
    }
#pragma unroll
    for (int i = 0; i < NC; ++i) {
        float wd = W1[(NZ + i) * H1 + j];
        const float4 y0 = *(const float4*)&ys[i][r0];
        const float4 y1 = *(const float4*)&ys[i][r0 + 4];
        acc[0] = fmaf(y0.x, wd, acc[0]); acc[1] = fmaf(y0.y, wd, acc[1]);
        acc[2] = fmaf(y0.z, wd, acc[2]); acc[3] = fmaf(y0.w, wd, acc[3]);
        acc[4] = fmaf(y1.x, wd, acc[4]); acc[5] = fmaf(y1.y, wd, acc[5]);
        acc[6] = fmaf(y1.z, wd, acc[6]); acc[7] = fmaf(y1.w, wd, acc[7]);
    }
    const float bb = b1[j];
    float v[8];
#pragma unroll
    for (int r = 0; r < 8; ++r) {
        v[r] = acc[r] + bb;
        a1[(b0 + r0 + r) * H1 + j] = v[r];
    }
    if (half) {
#pragma unroll
        for (int r = 0; r < 8; ++r) vsh[j][r] = v[r];
    }
    __syncthreads();
    if (!half) {
        double s = 0.0, s2 = 0.0;
#pragma unroll
        for (int r = 0; r < 8; ++r) {           // rows 0..7 in original order
            double dv = (double)v[r];
            s += dv; s2 += dv * dv;
        }
#pragma unroll
        for (int r = 0; r < 8; ++r) {           // rows 8..15 in original order
            double dv = (double)vsh[j][r];
            s += dv; s2 += dv * dv;
        }
        p1[blockIdx.x * H1 + j] = s;
        p2[blockIdx.x * H1 + j] = s2;
    }
}

// ---------------------------------------------------------------------------
// K2 (512 thr): BN stats from fp64 partials; 16 cols/block, COALESCED reads
// (R9's version read 64 distinct 2KB-strided lines per wave step, 8B used
// per 64B line). Thread (pg,c): parts pg, pg+32, ... ; LDS tree over pg.
// fp64 combine-tree differs from R9 at ~1e-16 relative — flip-safe.
__global__ __launch_bounds__(512) void k_stats(
    const double* __restrict__ p1, const double* __restrict__ p2,
    int nprt, int ncol,
    const float* __restrict__ gamma, const float* __restrict__ beta,
    float* __restrict__ scale, float* __restrict__ shift)
{
    const int t  = threadIdx.x;
    const int c  = t & 15, pg = t >> 4;
    const int j  = blockIdx.x * 16 + c;
    double s = 0.0, s2 = 0.0;
    for (int part = pg; part < nprt; part += 32) {
        s  += p1[(size_t)part * ncol + j];
        s2 += p2[(size_t)part * ncol + j];
    }
    __shared__ double ls[32][16], ls2[32][16];
    ls[pg][c] = s; ls2[pg][c] = s2;
    __syncthreads();
#pragma unroll
    for (int h = 16; h >= 1; h >>= 1) {
        if (pg < h) {
            ls[pg][c]  += ls[pg + h][c];
            ls2[pg][c] += ls2[pg + h][c];
        }
        __syncthreads();
    }
    if (t < 16) {
        const int jj = blockIdx.x * 16 + t;
        double S  = ls[0][t];
        double S2 = ls2[0][t];
        double mean = S * (1.0 / B_ROWS);
        double var  = S2 * (1.0 / B_ROWS) - mean * mean;
        double rstd = 1.0 / sqrt(var + 1e-5);
        double sc   = (double)gamma[jj] * rstd;
        scale[jj] = (float)sc;
        shift[jj] = (float)((double)beta[jj] - mean * sc);
    }
}

// ---------------------------------------------------------------------------
// K3 (512 thr): 16 rows/block; thread = 1 col x 2 rows. fp32 FMA accumulate;
// BN partial sums reassembled in fp64, original row order, via LDS.
__global__ __launch_bounds__(512) void k_a2(
    const float* __restrict__ a1,
    const float* __restrict__ sc1, const float* __restrict__ sh1,
    const float* __restrict__ W2, const float* __restrict__ b2,
    float* __restrict__ a2, double* __restrict__ p1, double* __restrict__ p2)
{
    const int t  = threadIdx.x;
    const int k  = t & 63;       // output col
    const int rg = t >> 6;       // row-group (== wave), rows rg*2, rg*2+1
    const int b0 = blockIdx.x * A2ROWS;
    const int r0 = rg * 2;

    __shared__ __align__(8) float hs[H1][18];   // stride 72B: 2-way banks max
    __shared__ float vsh[64][17];

    {
        const int jc = t & 255, rq = t >> 8;
        const float sct = sc1[jc], sht = sh1[jc];
#pragma unroll
        for (int rr = rq * 8; rr < rq * 8 + 8; ++rr) {
            float vv = a1[(size_t)(b0 + rr) * H1 + jc];
            hs[jc][rr] = fmaxf(fmaf(vv, sct, sht), 0.0f);
        }
    }
    __syncthreads();

    float acc0 = 0.0f, acc1 = 0.0f;
#pragma unroll 4
    for (int j = 0; j < H1; ++j) {
        float wd = W2[j * H2 + k];
        const float2 h2 = *(const float2*)&hs[j][r0];
        acc0 = fmaf(h2.x, wd, acc0);
        acc1 = fmaf(h2.y, wd, acc1);
    }
    const float bb = b2[k];
    float v0 = acc0 + bb;
    float v1 = acc1 + bb;
    a2[(b0 + r0 + 0) * H2 + k] = v0;
    a2[(b0 + r0 + 1) * H2 + k] = v1;
    vsh[k][r0]     = v0;
    vsh[k][r0 + 1] = v1;
    __syncthreads();
    if (t < 64) {
        double s = 0.0, s2 = 0.0;
#pragma unroll
        for (int r = 0; r < A2ROWS; ++r) {      // original order r = 0..15
            double dv = (double)vsh[t][r];
            s += dv; s2 += dv * dv;
        }
        p1[blockIdx.x * H2 + t] = s;
        p2[blockIdx.x * H2 + t] = s2;
    }
}

// ---------------------------------------------------------------------------
// K5: R9 batch-4 compute core VERBATIM + a 50-cycle wmax-reduce prologue
// (128 floats via 2-wave shfl; replaces memset node + global atomicMax —
// R10's regression was its 512KB/block BN2 reads, NOT this part).
__global__ __launch_bounds__(512)
__attribute__((amdgpu_waves_per_eu(4, 4)))
void k_main(
    const float* __restrict__ a2,
    const float* __restrict__ sc2, const float* __restrict__ sh2,
    const float* __restrict__ W3, const float* __restrict__ b3,
    const unsigned short* __restrict__ w3s, const float* __restrict__ wmax,
    const float* __restrict__ codebook, float* __restrict__ out)
{
    const int t    = threadIdx.x;
    const int wv   = t >> 6;           // wave 0..7
    const int lane = t & 63;
    const int quad = lane >> 4, col = lane & 15;
    const int b0   = blockIdx.x * RROWS;

    __shared__ __align__(16) float h2T[64][17];     // [j][r], padded
    __shared__ float fineT[NTILE][17];              // per-(tile16, row) bf16 max
    __shared__ float thrS[RROWS];
    __shared__ unsigned long long best[RROWS];
    __shared__ unsigned short wl[RROWS * NTILE];    // sized at true max: no overflow
    __shared__ int wlN;
    __shared__ int rowInd[RROWS];
    __shared__ float maxwS;
    __shared__ float mparts[2];

    if (t == 0) wlN = 0;
    if (t < 128) {                       // waves 0-1: reduce wmax[128]
        float m = wmax[t];
#pragma unroll
        for (int off = 32; off; off >>= 1) m = fmaxf(m, __shfl_xor(m, off));
        if ((t & 63) == 0) mparts[t >> 6] = m;
    }
    for (int q = t; q < RROWS * 64; q += 512) {
        int j = q >> 4, r = q & 15;
        float v = a2[(b0 + r) * H2 + j];
        h2T[j][r] = fmaxf(fmaf(v, sc2[j], sh2[j]), 0.0f);
    }
    __syncthreads();
    if (t == 0) maxwS = fmaxf(mparts[0], mparts[1]);

    // h fragments (bf16): lane holds h[r=col][k=quad*8+jj], k-halves 0/1
    short8 aF0, aF1;
#pragma unroll
    for (int jj = 0; jj < 8; ++jj) {
        aF0[jj] = (short)f2bf(h2T[quad * 8 + jj][col]);
        aF1[jj] = (short)f2bf(h2T[32 + quad * 8 + jj][col]);
    }

    // ---- Pass A: 8 segments x (2 half-batches x 4 tiles); swapped-operand
    //      MFMA -> lane holds logit[r=lane&15][c=T*16+quad*4+q] in acc[q] ----
    {
        const uint4*  wp = (const uint4*)w3s + (size_t)wv * 8192 + lane;
        const float4* bq = (const float4*)b3 + wv * 256 + quad;
        for (int s = 0; s < 8; ++s) {
#pragma unroll
            for (int hu = 0; hu < 2; ++hu) {
                uint4 c[4], d[4];
                float4 bb[4];
#pragma unroll
                for (int u = 0; u < 4; ++u) {
                    const int uu = hu * 4 + u;
                    c[u]  = wp[uu * 128];
                    d[u]  = wp[uu * 128 + 64];
                    bb[u] = bq[uu * 4];
                }
#pragma unroll
                for (int u = 0; u < 4; ++u) {
                    f32x4 acc = {bb[u].x, bb[u].y, bb[u].z, bb[u].w};
                    acc = __builtin_amdgcn_mfma_f32_16x16x32_bf16(
                              *(const short8*)&c[u], aF0, acc, 0, 0, 0);
                    acc = __builtin_amdgcn_mfma_f32_16x16x32_bf16(
                              *(const short8*)&d[u], aF1, acc, 0, 0, 0);
                    float m = fmaxf(fmaxf(acc[0], acc[1]), fmaxf(acc[2], acc[3]));
                    m = fmaxf(m, __shfl_xor(m, 16));
                    m = fmaxf(m, __shfl_xor(m, 32));
                    if (lane < 16)
                        fineT[(wv * 8 + s) * 8 + hu * 4 + u][lane] = m;
                }
            }
            wp += 1024; bq += 32;
        }
    }
    __syncthreads();

    // ---- Thresholds: all 512 threads; row = t>>5, 32 lanes per row ----
    {
        const int r = t >> 5, cc = t & 31;
        float s = fabsf(h2T[2 * cc][r]) + fabsf(h2T[2 * cc + 1][r]);
        float gmv = -1e30f;
#pragma unroll
        for (int k = 0; k < 16; ++k) gmv = fmaxf(gmv, fineT[cc + 32 * k][r]);
#pragma unroll
        for (int off = 1; off < 32; off <<= 1) {
            s   += __shfl_xor(s, off);
            gmv  = fmaxf(gmv, __shfl_xor(gmv, off));
        }
        if (cc == 0) {
            float e = s * maxwS * (1.0f / 256.0f);   // |dlogit| <= S*maxW*2^-8
            thrS[r] = gmv - (0.1068f + e + 1e-3f);
            best[r] = 0ull;
        }
    }
    __syncthreads();

    // ---- Worklist of qualifying (row, tile16) cells ----
    {
        const int r = t >> 5, cc = t & 31;
        const float th = thrS[r];
#pragma unroll
        for (int k = 0; k < 16; ++k) {
            const int T = cc + 32 * k;
            if (fineT[T][r] >= th) {
                int idx = atomicAdd(&wlN, 1);
                wl[idx] = (unsigned short)((r << 9) | T);
            }
        }
    }
    __syncthreads();

    // ---- Pass B: wave handles 4 cells (16 lanes each); exact fp32 ----
    {
        const int n = wlN;
        const int g = lane >> 4;       // cell slot within wave
        for (int i = wv * 4; i < n; i += 32) {
            const int  ci  = i + g;
            const bool act = (ci < n);
            const int  e   = act ? wl[ci] : 0;
            const int  r   = e >> 9;
            const int  T   = e & 511;
            const int  f   = T * 16 + col;
            float acc = b3[f];
            const float* wcol = W3 + f;
#pragma unroll 8
            for (int j = 0; j < 64; ++j) {
                acc = fmaf(h2T[j][r], *wcol, acc);
                wcol += FEATN;
            }
            if (act && acc >= thrS[r]) {
                float sc = acc + gumbel_g((unsigned)(b0 + r) * (unsigned)FEATN + (unsigned)f);
                unsigned long long pk = ((unsigned long long)fmono(sc) << 32)
                                      | (unsigned)(FEATN - 1 - f);
                atomicMax(&best[r], pk);
            }
        }
    }
    __syncthreads();
    if (t < RROWS) {
        rowInd[t] = (FEATN - 1 - (int)(best[t] & 0xFFFFFFFFull)) & (FEATN - 1);
    }
    __syncthreads();

    // ---- out[b,:] = codebook[ind,:] ----
    {
        const int rr = t >> 8, tt = t & 255;
        for (int rp = 0; rp < RROWS / 2; ++rp) {
            const int r = rp * 2 + rr;
            const int ind = rowInd[r];
            const float4* src = (const float4*)(codebook + (size_t)ind * FDIM);
            float4*       dst = (float4*)(out + (size_t)(b0 + r) * FDIM);
            dst[tt] = src[tt];
        }
    }
}

// ---------------------------------------------------------------------------
extern "C" void kernel_launch(void* const* d_in, const int* in_sizes, int n_in,
                              void* d_out, int out_size, void* d_ws, size_t ws_size,
                              hipStream_t stream)
{
    const float* x   = (const float*)d_in[0];
    const float* y   = (const float*)d_in[1];
    const float* W1  = (const float*)d_in[2];
    const float* b1  = (const float*)d_in[3];
    const float* g1  = (const float*)d_in[4];
    const float* be1 = (const float*)d_in[5];
    const float* W2  = (const float*)d_in[6];
    const float* b2  = (const float*)d_in[7];
    const float* g2  = (const float*)d_in[8];
    const float* be2 = (const float*)d_in[9];
    const float* W3  = (const float*)d_in[10];
    const float* b3  = (const float*)d_in[11];
    const float* cb  = (const float*)d_in[12];
    float* out = (float*)d_out;

    float* ws  = (float*)d_ws;
    float* a1  = ws;                          // 8 MB
    float* a2  = a1 + B_ROWS * H1;            // 2 MB
    float* sc1 = a2 + B_ROWS * H2;
    float* sh1 = sc1 + H1;
    float* sc2 = sh1 + H1;
    float* sh2 = sc2 + H2;
    double* p1 = (double*)(sh2 + H2);         // 1 MB
    double* p2 = p1 + A1BLKS * H1;            // 1 MB
    unsigned short* w3s = (unsigned short*)(p2 + A1BLKS * H1);  // 1 MB bf16
    float* wmax = (float*)(w3s + NTILE * 2 * 64 * 8);           // 128 f32

    // 5-node graph: no memset (wmax fully rewritten every launch).
    k_a1   <<<A1BLKS + CONVBLKS, 512, 0, stream>>>(x, y, W1, b1, W3,
                                                   a1, p1, p2, w3s, wmax);
    k_stats<<<H1 / 16, 512, 0, stream>>>(p1, p2, A1BLKS, H1, g1, be1, sc1, sh1);
    k_a2   <<<A2BLKS, 512, 0, stream>>>(a1, sc1, sh1, W2, b2, a2, p1, p2);
    k_stats<<<H2 / 16, 512, 0, stream>>>(p1, p2, A2BLKS, H2, g2, be2, sc2, sh2);
    k_main <<<B_ROWS / RROWS, 512, 0, stream>>>(a2, sc2, sh2, W3, b3,
                                                w3s, wmax, cb, out);
}

// Round 12
// 199.683 us; speedup vs baseline: 1.0573x; 1.0391x over previous
//
#include <hip/hip_runtime.h>
#include <math.h>

// ---------------------------------------------------------------------------
#define B_ROWS   8192
#define NZ       100
#define NC       2
#define H1       256
#define H2       64
#define FEATN    8192
#define FDIM     1024
#define RROWS    16            // rows per k_main block = MFMA M
#define NTILE    (FEATN / 16)  // 512 16-col MFMA tiles
#define A1ROWS   16
#define A1BLKS   (B_ROWS / A1ROWS)   // 512
#define CONVBLKS 128                 // w3 conversion blocks fused into k_a1 (512 thr)
#define A2ROWS   16
#define A2BLKS   (B_ROWS / A2ROWS)   // 512

typedef __attribute__((ext_vector_type(8))) short short8;
typedef __attribute__((ext_vector_type(4))) float f32x4;

// ---------------------------------------------------------------------------
// JAX threefry2x32, partitionable, key=(0,42), counter=(0, flat)
__device__ __forceinline__ unsigned rotl32(unsigned v, int r) {
    return (v << r) | (v >> (32 - r));
}
__device__ __forceinline__ unsigned threefry_bits(unsigned lo) {
    const unsigned ks0 = 0u, ks1 = 42u, ks2 = 0x1BD11BDAu ^ 42u;
    unsigned x0 = 0u + ks0;
    unsigned x1 = lo + ks1;
#define TF_R4(a,b,c,d) \
    x0 += x1; x1 = rotl32(x1,a); x1 ^= x0; \
    x0 += x1; x1 = rotl32(x1,b); x1 ^= x0; \
    x0 += x1; x1 = rotl32(x1,c); x1 ^= x0; \
    x0 += x1; x1 = rotl32(x1,d); x1 ^= x0;
    TF_R4(13,15,26,6);  x0 += ks1; x1 += ks2 + 1u;
    TF_R4(17,29,16,24); x0 += ks2; x1 += ks0 + 2u;
    TF_R4(13,15,26,6);  x0 += ks0; x1 += ks1 + 3u;
    TF_R4(17,29,16,24); x0 += ks1; x1 += ks2 + 4u;
    TF_R4(13,15,26,6);  x0 += ks2; x1 += ks0 + 5u;
#undef TF_R4
    return x0 ^ x1;
}
__device__ __forceinline__ float gumbel_g(unsigned flat) {
    unsigned bits = threefry_bits(flat);
    float u  = __uint_as_float((bits >> 9) | 0x3f800000u) - 1.0f;
    float U  = 0.001f * u;
    float t1 = U + 0.001f;
    float L1 = (float)log((double)t1);
    float A  = 0.001f - L1;
    float L2 = (float)log((double)A);
    return -L2;
}

// float -> bf16 RNE
__device__ __forceinline__ unsigned short f2bf(float x) {
    unsigned u = __float_as_uint(x);
    u += 0x7fffu + ((u >> 16) & 1u);
    return (unsigned short)(u >> 16);
}
// order-preserving float -> u32
__device__ __forceinline__ unsigned fmono(float x) {
    unsigned b = __float_as_uint(x);
    return (b & 0x80000000u) ? ~b : (b | 0x80000000u);
}

// ---------------------------------------------------------------------------
// K1 (512 thr): blocks [0,A1BLKS): a1 = concat(x,y)@W1 + b1 (fp32 FMA); BN1
//   partials (fp64, original row order) accumulate via native f64 atomicAdd
//   into S1/S2[8][H1] (slot = blockIdx&7, <=64 adds/address ~0.8us tail) —
//   replaces the stats1 kernel node.  NO cross-block fences (R8 lesson).
//     blocks [A1BLKS,..): convert W3 -> bf16 MFMA-B-fragment layout; per-block
//   max|W3| -> wmax[block] (all 128 slots written every run: no init needed).
__global__ __launch_bounds__(512) void k_a1(
    const float* __restrict__ x, const float* __restrict__ y,
    const float* __restrict__ W1, const float* __restrict__ b1,
    const float* __restrict__ W3,
    float* __restrict__ a1, double* __restrict__ S1, double* __restrict__ S2,
    unsigned short* __restrict__ w3s, float* __restrict__ wmax)
{
    const int t = threadIdx.x;

    if (blockIdx.x >= A1BLKS) {
        const int job  = (blockIdx.x - A1BLKS) * 512 + t;   // 0..65535
        const int T    = job >> 7;
        const int rem  = job & 127;
        const int kh   = rem >> 6;
        const int l    = rem & 63;
        const int quad = l >> 4, col = l & 15;
        const float* src = W3 + (size_t)(kh * 32 + quad * 8) * FEATN + T * 16 + col;
        unsigned short v[8];
        float mx = 0.0f;
#pragma unroll
        for (int jj = 0; jj < 8; ++jj) {
            float xv = src[(size_t)jj * FEATN];
            mx = fmaxf(mx, fabsf(xv));
            v[jj] = f2bf(xv);
        }
        uint4 o;
        o.x = (unsigned)v[0] | ((unsigned)v[1] << 16);
        o.y = (unsigned)v[2] | ((unsigned)v[3] << 16);
        o.z = (unsigned)v[4] | ((unsigned)v[5] << 16);
        o.w = (unsigned)v[6] | ((unsigned)v[7] << 16);
        ((uint4*)w3s)[job] = o;
#pragma unroll
        for (int off = 32; off; off >>= 1) mx = fmaxf(mx, __shfl_xor(mx, off));
        __shared__ float wred[8];
        if ((t & 63) == 0) wred[t >> 6] = mx;
        __syncthreads();
        if (t == 0) {
            float m = wred[0];
#pragma unroll
            for (int wq = 1; wq < 8; ++wq) m = fmaxf(m, wred[wq]);
            wmax[blockIdx.x - A1BLKS] = m;
        }
        return;
    }

    const int j    = t & 255;
    const int half = t >> 8;            // 0: rows 0-7, 1: rows 8-15
    const int b0   = blockIdx.x * A1ROWS;
    const int r0   = half * 8;

    // Transposed LDS x-tile: xs[i][r] -> broadcast ds_read_b128 in the loop.
    __shared__ __align__(16) float xs[NZ][16];
    __shared__ __align__(16) float ys[NC][16];
    __shared__ float vsh[256][8];       // half1's v values, for exact-order sums
    for (int q = t; q < A1ROWS * NZ; q += 512) {
        int r = q / NZ, i = q - r * NZ;
        xs[i][r] = x[(size_t)b0 * NZ + q];
    }
    if (t < A1ROWS * NC) {
        int r = t >> 1, i = t & 1;
        ys[i][r] = y[b0 * NC + t];
    }
    __syncthreads();

    float acc[8];
#pragma unroll
    for (int r = 0; r < 8; ++r) acc[r] = 0.0f;
    for (int i = 0; i < NZ; ++i) {
        float wd = W1[i * H1 + j];
        const float4 x0 = *(const float4*)&xs[i][r0];
        const float4 x1 = *(const float4*)&xs[i][r0 + 4];
        acc[0] = fmaf(x0.x, wd, acc[0]); acc[1] = fmaf(x0.y, wd, acc[1]);
        acc[2] = fmaf(x0.z, wd, acc[2]); acc[3] = fmaf(x0.w, wd, acc[3]);
        acc[4] = fmaf(x1.x, wd, acc[4]); acc[5] = fmaf(x1.y, wd, acc[5]);
        acc[6] = fmaf(x1.z, wd, acc[6]); acc[7] = fmaf(x1.w, wd, acc[7]);
    }
#pragma unroll
    for (int i = 0; i < NC; ++i) {
        float wd = W1[(NZ + i) * H1 + j];
        const float4 y0 = *(const float4*)&ys[i][r0];
        const float4 y1 = *(const float4*)&ys[i][r0 + 4];
        acc[0] = fmaf(y0.x, wd, acc[0]); acc[1] = fmaf(y0.y, wd, acc[1]);
        acc[2] = fmaf(y0.z, wd, acc[2]); acc[3] = fmaf(y0.w, wd, acc[3]);
        acc[4] = fmaf(y1.x, wd, acc[4]); acc[5] = fmaf(y1.y, wd, acc[5]);
        acc[6] = fmaf(y1.z, wd, acc[6]); acc[7] = fmaf(y1.w, wd, acc[7]);
    }
    const float bb = b1[j];
    float v[8];
#pragma unroll
    for (int r = 0; r < 8; ++r) {
        v[r] = acc[r] + bb;
        a1[(b0 + r0 + r) * H1 + j] = v[r];
    }
    if (half) {
#pragma unroll
        for (int r = 0; r < 8; ++r) vsh[j][r] = v[r];
    }
    __syncthreads();
    if (!half) {
        double s = 0.0, s2 = 0.0;
#pragma unroll
        for (int r = 0; r < 8; ++r) {           // rows 0..7 in original order
            double dv = (double)v[r];
            s += dv; s2 += dv * dv;
        }
#pragma unroll
        for (int r = 0; r < 8; ++r) {           // rows 8..15 in original order
            double dv = (double)vsh[j][r];
            s += dv; s2 += dv * dv;
        }
        const int slot = blockIdx.x & 7;
        atomicAdd(&S1[slot * H1 + j], s);       // native f64 atomic (CDNA)
        atomicAdd(&S2[slot * H1 + j], s2);
    }
}

// ---------------------------------------------------------------------------
// K3 (512 thr): prologue finalizes BN1 stats from S1/S2 (32 KB/block — the
// cheap version of R10's 512 KB/block mistake); 16 rows/block matmul, thread
// = 1 col x 2 rows, fp32 FMA; BN2 partials in fp64 original row order,
// accumulated via f64 atomicAdd into S1b/S2b[8][H2] — replaces stats2 node.
__global__ __launch_bounds__(512) void k_a2(
    const float* __restrict__ a1,
    const float* __restrict__ g1, const float* __restrict__ be1,
    const double* __restrict__ S1, const double* __restrict__ S2,
    const float* __restrict__ W2, const float* __restrict__ b2,
    float* __restrict__ a2, double* __restrict__ S1b, double* __restrict__ S2b)
{
    const int t  = threadIdx.x;
    const int k  = t & 63;       // output col
    const int rg = t >> 6;       // row-group (== wave), rows rg*2, rg*2+1
    const int b0 = blockIdx.x * A2ROWS;
    const int r0 = rg * 2;

    __shared__ __align__(8) float hs[H1][18];   // stride 72B: 2-way banks max
    __shared__ float vsh[64][17];
    __shared__ float scs[H1], shs[H1];

    if (t < H1) {
        double s = 0.0, s2 = 0.0;
#pragma unroll
        for (int p = 0; p < 8; ++p) {
            s  += S1[p * H1 + t];
            s2 += S2[p * H1 + t];
        }
        double mean = s * (1.0 / B_ROWS);
        double var  = s2 * (1.0 / B_ROWS) - mean * mean;
        double rstd = 1.0 / sqrt(var + 1e-5);
        double sc   = (double)g1[t] * rstd;
        scs[t] = (float)sc;
        shs[t] = (float)((double)be1[t] - mean * sc);
    }
    __syncthreads();

    {
        const int jc = t & 255, rq = t >> 8;
        const float sct = scs[jc], sht = shs[jc];
#pragma unroll
        for (int rr = rq * 8; rr < rq * 8 + 8; ++rr) {
            float vv = a1[(size_t)(b0 + rr) * H1 + jc];
            hs[jc][rr] = fmaxf(fmaf(vv, sct, sht), 0.0f);
        }
    }
    __syncthreads();

    float acc0 = 0.0f, acc1 = 0.0f;
#pragma unroll 4
    for (int j = 0; j < H1; ++j) {
        float wd = W2[j * H2 + k];
        const float2 h2 = *(const float2*)&hs[j][r0];
        acc0 = fmaf(h2.x, wd, acc0);
        acc1 = fmaf(h2.y, wd, acc1);
    }
    const float bb = b2[k];
    float v0 = acc0 + bb;
    float v1 = acc1 + bb;
    a2[(b0 + r0 + 0) * H2 + k] = v0;
    a2[(b0 + r0 + 1) * H2 + k] = v1;
    vsh[k][r0]     = v0;
    vsh[k][r0 + 1] = v1;
    __syncthreads();
    if (t < 64) {
        double s = 0.0, s2 = 0.0;
#pragma unroll
        for (int r = 0; r < A2ROWS; ++r) {      // original order r = 0..15
            double dv = (double)vsh[t][r];
            s += dv; s2 += dv * dv;
        }
        const int slot = blockIdx.x & 7;
        atomicAdd(&S1b[slot * H2 + t], s);
        atomicAdd(&S2b[slot * H2 + t], s2);
    }
}

// ---------------------------------------------------------------------------
// K5: R11 batch-4 compute core VERBATIM + cheap fused prologue:
//   (a) BN2 finalize from S1b/S2b: 8 KB/block (R10's regression was its
//       512 KB/block reads — this is 64x smaller, ~0.2us);
//   (b) wmax[128] reduce via 2-wave shfl (replaces memset + atomicMax).
__global__ __launch_bounds__(512)
__attribute__((amdgpu_waves_per_eu(4, 4)))
void k_main(
    const float* __restrict__ a2,
    const float* __restrict__ g2, const float* __restrict__ be2,
    const double* __restrict__ S1b, const double* __restrict__ S2b,
    const float* __restrict__ W3, const float* __restrict__ b3,
    const unsigned short* __restrict__ w3s, const float* __restrict__ wmax,
    const float* __restrict__ codebook, float* __restrict__ out)
{
    const int t    = threadIdx.x;
    const int wv   = t >> 6;           // wave 0..7
    const int lane = t & 63;
    const int quad = lane >> 4, col = lane & 15;
    const int b0   = blockIdx.x * RROWS;

    __shared__ __align__(16) float h2T[64][17];     // [j][r], padded
    __shared__ float fineT[NTILE][17];              // per-(tile16, row) bf16 max
    __shared__ float thrS[RROWS];
    __shared__ unsigned long long best[RROWS];
    __shared__ unsigned short wl[RROWS * NTILE];    // sized at true max: no overflow
    __shared__ int wlN;
    __shared__ int rowInd[RROWS];
    __shared__ float maxwS;
    __shared__ float mparts[2];
    __shared__ float sc2S[H2], sh2S[H2];

    if (t == 0) wlN = 0;
    if (t < 128) {                       // waves 0-1: reduce wmax[128]
        float m = wmax[t];
#pragma unroll
        for (int off = 32; off; off >>= 1) m = fmaxf(m, __shfl_xor(m, off));
        if ((t & 63) == 0) mparts[t >> 6] = m;
    }
    if (t < H2) {                        // wave 0: BN2 finalize (8 KB)
        double s = 0.0, s2 = 0.0;
#pragma unroll
        for (int p = 0; p < 8; ++p) {
            s  += S1b[p * H2 + t];
            s2 += S2b[p * H2 + t];
        }
        double mean = s * (1.0 / B_ROWS);
        double var  = s2 * (1.0 / B_ROWS) - mean * mean;
        double rstd = 1.0 / sqrt(var + 1e-5);
        double sc   = (double)g2[t] * rstd;
        sc2S[t] = (float)sc;
        sh2S[t] = (float)((double)be2[t] - mean * sc);
    }
    __syncthreads();
    for (int q = t; q < RROWS * 64; q += 512) {
        int j = q >> 4, r = q & 15;
        float v = a2[(b0 + r) * H2 + j];
        h2T[j][r] = fmaxf(fmaf(v, sc2S[j], sh2S[j]), 0.0f);
    }
    __syncthreads();
    if (t == 0) maxwS = fmaxf(mparts[0], mparts[1]);

    // h fragments (bf16): lane holds h[r=col][k=quad*8+jj], k-halves 0/1
    short8 aF0, aF1;
#pragma unroll
    for (int jj = 0; jj < 8; ++jj) {
        aF0[jj] = (short)f2bf(h2T[quad * 8 + jj][col]);
        aF1[jj] = (short)f2bf(h2T[32 + quad * 8 + jj][col]);
    }

    // ---- Pass A: 8 segments x (2 half-batches x 4 tiles); swapped-operand
    //      MFMA -> lane holds logit[r=lane&15][c=T*16+quad*4+q] in acc[q] ----
    {
        const uint4*  wp = (const uint4*)w3s + (size_t)wv * 8192 + lane;
        const float4* bq = (const float4*)b3 + wv * 256 + quad;
        for (int s = 0; s < 8; ++s) {
#pragma unroll
            for (int hu = 0; hu < 2; ++hu) {
                uint4 c[4], d[4];
                float4 bb[4];
#pragma unroll
                for (int u = 0; u < 4; ++u) {
                    const int uu = hu * 4 + u;
                    c[u]  = wp[uu * 128];
                    d[u]  = wp[uu * 128 + 64];
                    bb[u] = bq[uu * 4];
                }
#pragma unroll
                for (int u = 0; u < 4; ++u) {
                    f32x4 acc = {bb[u].x, bb[u].y, bb[u].z, bb[u].w};
                    acc = __builtin_amdgcn_mfma_f32_16x16x32_bf16(
                              *(const short8*)&c[u], aF0, acc, 0, 0, 0);
                    acc = __builtin_amdgcn_mfma_f32_16x16x32_bf16(
                              *(const short8*)&d[u], aF1, acc, 0, 0, 0);
                    float m = fmaxf(fmaxf(acc[0], acc[1]), fmaxf(acc[2], acc[3]));
                    m = fmaxf(m, __shfl_xor(m, 16));
                    m = fmaxf(m, __shfl_xor(m, 32));
                    if (lane < 16)
                        fineT[(wv * 8 + s) * 8 + hu * 4 + u][lane] = m;
                }
            }
            wp += 1024; bq += 32;
        }
    }
    __syncthreads();

    // ---- Thresholds: all 512 threads; row = t>>5, 32 lanes per row ----
    {
        const int r = t >> 5, cc = t & 31;
        float s = fabsf(h2T[2 * cc][r]) + fabsf(h2T[2 * cc + 1][r]);
        float gmv = -1e30f;
#pragma unroll
        for (int k = 0; k < 16; ++k) gmv = fmaxf(gmv, fineT[cc + 32 * k][r]);
#pragma unroll
        for (int off = 1; off < 32; off <<= 1) {
            s   += __shfl_xor(s, off);
            gmv  = fmaxf(gmv, __shfl_xor(gmv, off));
        }
        if (cc == 0) {
            float e = s * maxwS * (1.0f / 256.0f);   // |dlogit| <= S*maxW*2^-8
            thrS[r] = gmv - (0.1068f + e + 1e-3f);
            best[r] = 0ull;
        }
    }
    __syncthreads();

    // ---- Worklist of qualifying (row, tile16) cells ----
    {
        const int r = t >> 5, cc = t & 31;
        const float th = thrS[r];
#pragma unroll
        for (int k = 0; k < 16; ++k) {
            const int T = cc + 32 * k;
            if (fineT[T][r] >= th) {
                int idx = atomicAdd(&wlN, 1);
                wl[idx] = (unsigned short)((r << 9) | T);
            }
        }
    }
    __syncthreads();

    // ---- Pass B: wave handles 4 cells (16 lanes each); exact fp32 ----
    {
        const int n = wlN;
        const int g = lane >> 4;       // cell slot within wave
        for (int i = wv * 4; i < n; i += 32) {
            const int  ci  = i + g;
            const bool act = (ci < n);
            const int  e   = act ? wl[ci] : 0;
            const int  r   = e >> 9;
            const int  T   = e & 511;
            const int  f   = T * 16 + col;
            float acc = b3[f];
            const float* wcol = W3 + f;
#pragma unroll 8
            for (int j = 0; j < 64; ++j) {
                acc = fmaf(h2T[j][r], *wcol, acc);
                wcol += FEATN;
            }
            if (act && acc >= thrS[r]) {
                float sc = acc + gumbel_g((unsigned)(b0 + r) * (unsigned)FEATN + (unsigned)f);
                unsigned long long pk = ((unsigned long long)fmono(sc) << 32)
                                      | (unsigned)(FEATN - 1 - f);
                atomicMax(&best[r], pk);
            }
        }
    }
    __syncthreads();
    if (t < RROWS) {
        rowInd[t] = (FEATN - 1 - (int)(best[t] & 0xFFFFFFFFull)) & (FEATN - 1);
    }
    __syncthreads();

    // ---- out[b,:] = codebook[ind,:] ----
    {
        const int rr = t >> 8, tt = t & 255;
        for (int rp = 0; rp < RROWS / 2; ++rp) {
            const int r = rp * 2 + rr;
            const int ind = rowInd[r];
            const float4* src = (const float4*)(codebook + (size_t)ind * FDIM);
            float4*       dst = (float4*)(out + (size_t)(b0 + r) * FDIM);
            dst[tt] = src[tt];
        }
    }
}

// ---------------------------------------------------------------------------
extern "C" void kernel_launch(void* const* d_in, const int* in_sizes, int n_in,
                              void* d_out, int out_size, void* d_ws, size_t ws_size,
                              hipStream_t stream)
{
    const float* x   = (const float*)d_in[0];
    const float* y   = (const float*)d_in[1];
    const float* W1  = (const float*)d_in[2];
    const float* b1  = (const float*)d_in[3];
    const float* g1  = (const float*)d_in[4];
    const float* be1 = (const float*)d_in[5];
    const float* W2  = (const float*)d_in[6];
    const float* b2  = (const float*)d_in[7];
    const float* g2  = (const float*)d_in[8];
    const float* be2 = (const float*)d_in[9];
    const float* W3  = (const float*)d_in[10];
    const float* b3  = (const float*)d_in[11];
    const float* cb  = (const float*)d_in[12];
    float* out = (float*)d_out;

    float* ws  = (float*)d_ws;
    float* a1  = ws;                              // 8 MB
    float* a2  = a1 + B_ROWS * H1;                // 2 MB
    double* S1  = (double*)(a2 + B_ROWS * H2);    // [8][H1] fp64, 16 KB
    double* S2  = S1 + 8 * H1;                    // 16 KB
    double* S1b = S2 + 8 * H1;                    // [8][H2] fp64, 4 KB
    double* S2b = S1b + 8 * H2;                   // 4 KB
    unsigned short* w3s = (unsigned short*)(S2b + 8 * H2);      // 1 MB bf16
    float* wmax = (float*)(w3s + H2 * FEATN);                   // 128 f32

    // 4-node graph: memset zeroes the atomic accumulators (S1,S2,S1b,S2b
    // contiguous, 40 KB); both stats kernels fused into consumers' prologues.
    hipMemsetAsync(S1, 0, (8 * H1 * 2 + 8 * H2 * 2) * sizeof(double), stream);
    k_a1 <<<A1BLKS + CONVBLKS, 512, 0, stream>>>(x, y, W1, b1, W3,
                                                 a1, S1, S2, w3s, wmax);
    k_a2 <<<A2BLKS, 512, 0, stream>>>(a1, g1, be1, S1, S2, W2, b2,
                                      a2, S1b, S2b);
    k_main <<<B_ROWS / RROWS, 512, 0, stream>>>(a2, g2, be2, S1b, S2b,
                                                W3, b3, w3s, wmax, cb, out);
}